// Round 1
// baseline (2117.781 us; speedup 1.0000x reference)
//
#include <hip/hip_runtime.h>
#include <cstdint>
#include <cstddef>

typedef __attribute__((ext_vector_type(8))) short bf16x8;
typedef __attribute__((ext_vector_type(4))) float f32x4;

#define DEV __device__ __forceinline__

DEV unsigned short f2bf(float f) {
  union { float f; unsigned u; } v; v.f = f;
  unsigned r = (v.u + 0x7FFFu + ((v.u >> 16) & 1u)) >> 16;   // RNE
  return (unsigned short)r;
}

DEV void gload16(const void* g, void* l) {
  // async global->LDS, 16B per lane; LDS dest must be wave-uniform base (+lane*16 implicit)
  __builtin_amdgcn_global_load_lds(
      (__attribute__((address_space(1))) void*)const_cast<void*>(g),
      (__attribute__((address_space(3))) void*)l,
      16, 0, 0);
}

// ---------------- elementwise kernels ----------------

__global__ __launch_bounds__(256) void f2bf_kernel(const float* __restrict__ in,
                                                   unsigned short* __restrict__ out, int n4) {
  int i = blockIdx.x * 256 + threadIdx.x;
  if (i < n4) {
    float4 v = ((const float4*)in)[i];
    ushort4 o;
    o.x = f2bf(v.x); o.y = f2bf(v.y); o.z = f2bf(v.z); o.w = f2bf(v.w);
    ((ushort4*)out)[i] = o;
  }
}

// one block per row of 1024 f32; out bf16
__global__ __launch_bounds__(256) void rmsnorm_kernel(const float* __restrict__ x,
                                                      const float* __restrict__ w,
                                                      unsigned short* __restrict__ o) {
  const int row = blockIdx.x;
  const int tid = threadIdx.x;
  float4 v = ((const float4*)x)[(size_t)row * 256 + tid];
  float s = v.x * v.x + v.y * v.y + v.z * v.z + v.w * v.w;
#pragma unroll
  for (int m = 32; m > 0; m >>= 1) s += __shfl_xor(s, m);
  __shared__ float red[4];
  if ((tid & 63) == 0) red[tid >> 6] = s;
  __syncthreads();
  float tot = red[0] + red[1] + red[2] + red[3];
  float inv = rsqrtf(tot * (1.0f / 1024.0f) + 1e-6f);
  float4 wv = ((const float4*)w)[tid];
  ushort4 ov;
  ov.x = f2bf(v.x * inv * wv.x);
  ov.y = f2bf(v.y * inv * wv.y);
  ov.z = f2bf(v.z * inv * wv.z);
  ov.w = f2bf(v.w * inv * wv.w);
  ((ushort4*)o)[(size_t)row * 256 + tid] = ov;
}

// out[row,:] (+)= probs[row,d] * x[row,:]   (one block per row)
__global__ __launch_bounds__(256) void accum_kernel(const float* __restrict__ x,
                                                    const float* __restrict__ probs,
                                                    float* __restrict__ out, int d, int init) {
  const int row = blockIdx.x;
  const int tid = threadIdx.x;
  const float p = probs[(size_t)row * 4 + d];
  const size_t i = (size_t)row * 256 + tid;
  float4 xv = ((const float4*)x)[i];
  float4 ov;
  if (init) { ov.x = 0.f; ov.y = 0.f; ov.z = 0.f; ov.w = 0.f; }
  else ov = ((const float4*)out)[i];
  ov.x += p * xv.x; ov.y += p * xv.y; ov.z += p * xv.z; ov.w += p * xv.w;
  ((float4*)out)[i] = ov;
}

// ---------------- GEMM: C = A @ W^T, A (M,K) bf16 row-major, W (N,K) bf16 row-major ----------------
// EPI: 0 = store bf16, 1 = gelu(exact) -> bf16, 2 = f32 out = Res + acc
template <int EPI>
__global__ __launch_bounds__(256) void gemm_bf16(const unsigned short* __restrict__ A,
                                                 const unsigned short* __restrict__ W,
                                                 unsigned short* __restrict__ Ob,
                                                 float* __restrict__ Of,
                                                 const float* __restrict__ Res,
                                                 int M, int N, int K) {
  __shared__ alignas(16) unsigned short As[128 * 64];
  __shared__ alignas(16) unsigned short Bs[128 * 64];
  const int tid = threadIdx.x;
  const int lane = tid & 63;
  const int wave = tid >> 6;
  const int wr = wave >> 1, wc = wave & 1;
  const int brow = blockIdx.y * 128;
  const int bcol = blockIdx.x * 128;

  f32x4 acc[4][4] = {};

  const int sr = tid >> 3;         // 0..31
  const int sc = (tid & 7) << 3;   // 0,8,..,56

  const int ro = lane & 15;
  const int rg = lane >> 4;

  for (int kt = 0; kt < K; kt += 64) {
#pragma unroll
    for (int i = 0; i < 4; i++) {
      gload16(A + (size_t)(brow + i * 32 + sr) * K + kt + sc, &As[i * 2048 + wave * 512]);
      gload16(W + (size_t)(bcol + i * 32 + sr) * K + kt + sc, &Bs[i * 2048 + wave * 512]);
    }
    __syncthreads();
#pragma unroll
    for (int kk = 0; kk < 2; kk++) {
      const int ko = kk * 32 + rg * 8;
      bf16x8 av[4], bv[4];
#pragma unroll
      for (int m2 = 0; m2 < 4; m2++)
        av[m2] = *(const bf16x8*)&As[(wr * 64 + m2 * 16 + ro) * 64 + ko];
#pragma unroll
      for (int n2 = 0; n2 < 4; n2++)
        bv[n2] = *(const bf16x8*)&Bs[(wc * 64 + n2 * 16 + ro) * 64 + ko];
#pragma unroll
      for (int m2 = 0; m2 < 4; m2++)
#pragma unroll
        for (int n2 = 0; n2 < 4; n2++)
          acc[m2][n2] = __builtin_amdgcn_mfma_f32_16x16x32_bf16(av[m2], bv[n2], acc[m2][n2], 0, 0, 0);
    }
    __syncthreads();
  }

#pragma unroll
  for (int m2 = 0; m2 < 4; m2++) {
#pragma unroll
    for (int i = 0; i < 4; i++) {
      const int row = brow + wr * 64 + m2 * 16 + rg * 4 + i;
#pragma unroll
      for (int n2 = 0; n2 < 4; n2++) {
        const int col = bcol + wc * 64 + n2 * 16 + ro;
        const size_t idx = (size_t)row * N + col;
        float v = acc[m2][n2][i];
        if (EPI == 0) {
          Ob[idx] = f2bf(v);
        } else if (EPI == 1) {
          float g = 0.5f * v * (1.0f + erff(v * 0.70710678118f));
          Ob[idx] = f2bf(g);
        } else {
          Of[idx] = Res[idx] + v;
        }
      }
    }
  }
}

// ---------------- flash attention ----------------
// qkv: (B*T, 3072) bf16, layout [q(0:1024) | k(1024:2048) | v(2048:3072)], head h at h*64.
// grid: (T/64, B*H). 4 waves/block, 16 q-rows per wave. Online softmax.
__global__ __launch_bounds__(256) void attn_kernel(const unsigned short* __restrict__ qkv,
                                                   unsigned short* __restrict__ ob) {
  __shared__ alignas(16) unsigned short kt[64][72];   // K tile [key][d], +8 pad
  __shared__ alignas(16) unsigned short vt[64][72];   // V^T tile [d][key]
  __shared__ alignas(16) unsigned short pt[4][16][72];// per-wave P tile [q][key]
  const int tid = threadIdx.x, lane = tid & 63, wave = tid >> 6;
  const int bh = blockIdx.y, b = bh >> 4, h = bh & 15;
  const size_t base = (size_t)b * 1024 * 3072 + (size_t)h * 64;
  const unsigned short* qp = qkv + base;
  const unsigned short* kp = qkv + base + 1024;
  const unsigned short* vp = qkv + base + 2048;
  const int q0 = blockIdx.x * 64 + wave * 16;
  const int ro = lane & 15, rg = lane >> 4;

  bf16x8 aq[2];
  aq[0] = *(const bf16x8*)&qp[(size_t)(q0 + ro) * 3072 + rg * 8];
  aq[1] = *(const bf16x8*)&qp[(size_t)(q0 + ro) * 3072 + 32 + rg * 8];

  f32x4 oacc[4] = {};
  float mrow[4] = {-1e30f, -1e30f, -1e30f, -1e30f};
  float lrow[4] = {0.f, 0.f, 0.f, 0.f};

  for (int t0 = 0; t0 < 1024; t0 += 64) {
    // stage K tile and transposed V tile
#pragma unroll
    for (int it = 0; it < 2; it++) {
      const int c = it * 256 + tid;
      const int r = c >> 3, cl = (c & 7) << 3;
      uint4 kd = *(const uint4*)&kp[(size_t)(t0 + r) * 3072 + cl];
      *(uint4*)&kt[r][cl] = kd;
      uint4 vd = *(const uint4*)&vp[(size_t)(t0 + r) * 3072 + cl];
      const unsigned short* ve = (const unsigned short*)&vd;
#pragma unroll
      for (int j = 0; j < 8; j++) vt[cl + j][r] = ve[j];
    }
    __syncthreads();

    // S = Q K^T (16 q-rows x 64 keys per wave)
    f32x4 sf[4] = {};
#pragma unroll
    for (int kk = 0; kk < 2; kk++) {
      const int ko = kk * 32 + rg * 8;
#pragma unroll
      for (int n2 = 0; n2 < 4; n2++) {
        bf16x8 bk = *(const bf16x8*)&kt[n2 * 16 + ro][ko];
        sf[n2] = __builtin_amdgcn_mfma_f32_16x16x32_bf16(aq[kk], bk, sf[n2], 0, 0, 0);
      }
    }
    float pv[4][4];
#pragma unroll
    for (int n2 = 0; n2 < 4; n2++)
#pragma unroll
      for (int i = 0; i < 4; i++) pv[n2][i] = sf[n2][i] * 0.125f;

    float rmax[4];
#pragma unroll
    for (int i = 0; i < 4; i++)
      rmax[i] = fmaxf(fmaxf(pv[0][i], pv[1][i]), fmaxf(pv[2][i], pv[3][i]));
#pragma unroll
    for (int msk = 1; msk < 16; msk <<= 1)
#pragma unroll
      for (int i = 0; i < 4; i++) rmax[i] = fmaxf(rmax[i], __shfl_xor(rmax[i], msk));

    float alpha[4];
#pragma unroll
    for (int i = 0; i < 4; i++) {
      float mn = fmaxf(mrow[i], rmax[i]);
      alpha[i] = __expf(mrow[i] - mn);
      mrow[i] = mn;
    }
    float rsum[4] = {0.f, 0.f, 0.f, 0.f};
#pragma unroll
    for (int n2 = 0; n2 < 4; n2++)
#pragma unroll
      for (int i = 0; i < 4; i++) {
        pv[n2][i] = __expf(pv[n2][i] - mrow[i]);
        rsum[i] += pv[n2][i];
      }
#pragma unroll
    for (int msk = 1; msk < 16; msk <<= 1)
#pragma unroll
      for (int i = 0; i < 4; i++) rsum[i] += __shfl_xor(rsum[i], msk);
#pragma unroll
    for (int i = 0; i < 4; i++) lrow[i] = lrow[i] * alpha[i] + rsum[i];
#pragma unroll
    for (int n2 = 0; n2 < 4; n2++)
#pragma unroll
      for (int i = 0; i < 4; i++) oacc[n2][i] *= alpha[i];

    // P -> LDS (wave-local), then consume as MFMA A fragments
#pragma unroll
    for (int n2 = 0; n2 < 4; n2++)
#pragma unroll
      for (int i = 0; i < 4; i++) pt[wave][rg * 4 + i][n2 * 16 + ro] = f2bf(pv[n2][i]);
    asm volatile("" ::: "memory");  // keep ds_write before ds_read; same-wave DS ops are in-order

    // O += P @ V
#pragma unroll
    for (int kk = 0; kk < 2; kk++) {
      const int ko = kk * 32 + rg * 8;
      bf16x8 ap = *(const bf16x8*)&pt[wave][ro][ko];
#pragma unroll
      for (int n2 = 0; n2 < 4; n2++) {
        bf16x8 bv2 = *(const bf16x8*)&vt[n2 * 16 + ro][ko];
        oacc[n2] = __builtin_amdgcn_mfma_f32_16x16x32_bf16(ap, bv2, oacc[n2], 0, 0, 0);
      }
    }
    __syncthreads();
  }

#pragma unroll
  for (int n2 = 0; n2 < 4; n2++)
#pragma unroll
    for (int i = 0; i < 4; i++) {
      const int qrow = q0 + rg * 4 + i;
      float v = oacc[n2][i] / lrow[i];
      ob[((size_t)b * 1024 + qrow) * 1024 + h * 64 + n2 * 16 + ro] = f2bf(v);
    }
}

// ---------------- host ----------------

extern "C" void kernel_launch(void* const* d_in, const int* in_sizes, int n_in,
                              void* d_out, int out_size, void* d_ws, size_t ws_size,
                              hipStream_t stream) {
  const float* x = (const float*)d_in[0];
  // d_in[1] = depths (unused in soft mode)
  const float* probs = (const float*)d_in[2];
  const float* n1w = (const float*)d_in[3];
  const float* qkvw = (const float*)d_in[4];
  const float* outw = (const float*)d_in[5];
  const float* n2w = (const float*)d_in[6];
  const float* fc1w = (const float*)d_in[7];
  const float* fc2w = (const float*)d_in[8];
  float* out = (float*)d_out;

  const int B = 8, T = 1024, C = 1024;
  const int M = B * T;  // 8192

  char* ws = (char*)d_ws;
  size_t off = 0;
  auto alloc = [&](size_t bytes) {
    void* p = ws + off;
    off += (bytes + 255) & ~(size_t)255;
    return p;
  };
  unsigned short* wqkv = (unsigned short*)alloc((size_t)3072 * 1024 * 2);
  unsigned short* wout = (unsigned short*)alloc((size_t)1024 * 1024 * 2);
  unsigned short* wfc1 = (unsigned short*)alloc((size_t)4096 * 1024 * 2);
  unsigned short* wfc2 = (unsigned short*)alloc((size_t)1024 * 4096 * 2);
  float* xb = (float*)alloc((size_t)M * C * 4);
  unsigned short* xn = (unsigned short*)alloc((size_t)M * C * 2);
  char* big = (char*)alloc((size_t)M * 4096 * 2);  // 64MB region
  unsigned short* qkvb = (unsigned short*)big;                          // (M,3072) bf16
  unsigned short* obuf = (unsigned short*)(big + (size_t)M * 3072 * 2); // (M,1024) bf16
  unsigned short* gbuf = (unsigned short*)big;                          // (M,4096) bf16 (reuses qkv+o)

  // convert weights to bf16
  f2bf_kernel<<<(3072 * 1024 / 4 + 255) / 256, 256, 0, stream>>>(qkvw, wqkv, 3072 * 1024 / 4);
  f2bf_kernel<<<(1024 * 1024 / 4 + 255) / 256, 256, 0, stream>>>(outw, wout, 1024 * 1024 / 4);
  f2bf_kernel<<<(4096 * 1024 / 4 + 255) / 256, 256, 0, stream>>>(fc1w, wfc1, 4096 * 1024 / 4);
  f2bf_kernel<<<(4096 * 1024 / 4 + 255) / 256, 256, 0, stream>>>(fc2w, wfc2, 4096 * 1024 / 4);

  // working copy of x (residual stream, f32)
  hipMemcpyAsync(xb, x, (size_t)M * C * 4, hipMemcpyDeviceToDevice, stream);

  for (int d = 0; d < 4; d++) {
    rmsnorm_kernel<<<M, 256, 0, stream>>>(xb, n1w, xn);
    gemm_bf16<0><<<dim3(3072 / 128, M / 128), 256, 0, stream>>>(xn, wqkv, qkvb, nullptr, nullptr,
                                                                M, 3072, 1024);
    attn_kernel<<<dim3(T / 64, B * 16), 256, 0, stream>>>(qkvb, obuf);
    gemm_bf16<2><<<dim3(1024 / 128, M / 128), 256, 0, stream>>>(obuf, wout, nullptr, xb, xb,
                                                                M, 1024, 1024);
    rmsnorm_kernel<<<M, 256, 0, stream>>>(xb, n2w, xn);
    gemm_bf16<1><<<dim3(4096 / 128, M / 128), 256, 0, stream>>>(xn, wfc1, gbuf, nullptr, nullptr,
                                                                M, 4096, 1024);
    gemm_bf16<2><<<dim3(1024 / 128, M / 128), 256, 0, stream>>>(gbuf, wfc2, nullptr, xb, xb,
                                                                M, 1024, 4096);
    accum_kernel<<<M, 256, 0, stream>>>(xb, probs, out, d, d == 0 ? 1 : 0);
  }
}